// Round 6
// baseline (540.813 us; speedup 1.0000x reference)
//
#include <hip/hip_runtime.h>
#include <hip/hip_bf16.h>
#include <stdint.h>

// Problem constants
#define BATCH 16
#define SEQ   1024
#define HIDN  1024
#define NH    16
#define HD    64
#define PBSTRIDE 1025  // pos_bias last-dim stride (2*512+1)

typedef __attribute__((ext_vector_type(8))) short short8;
typedef __attribute__((ext_vector_type(4))) short short4v;
typedef __attribute__((ext_vector_type(4))) float f32x4;

__device__ __forceinline__ float bf2f(short x) {
    unsigned int u = ((unsigned int)(unsigned short)x) << 16;
    union { unsigned int u; float f; } c; c.u = u; return c.f;
}
__device__ __forceinline__ short f2bf(float f) {
    union { float f; unsigned int u; } c; c.f = f;
    unsigned int r = c.u + 0x7FFFu + ((c.u >> 16) & 1u);  // RNE
    return (short)(r >> 16);
}
__device__ __forceinline__ unsigned pack2(short lo, short hi) {
    return ((unsigned)(unsigned short)lo) | (((unsigned)(unsigned short)hi) << 16);
}

typedef __attribute__((address_space(1))) void gvoid;
typedef __attribute__((address_space(3))) void svoid;
__device__ __forceinline__ void gload_lds16(const void* g, void* l) {
    __builtin_amdgcn_global_load_lds((gvoid*)g, (svoid*)l, 16, 0, 0);
}

// -------- weight conversion fp32 -> bf16 --------
__global__ void convw_k(const float* __restrict__ src, short* __restrict__ dst) {
    int i = (blockIdx.x * 256 + threadIdx.x) * 4;
    float4 f = *(const float4*)(src + i);
    short4v o;
    o[0] = f2bf(f.x); o[1] = f2bf(f.y); o[2] = f2bf(f.z); o[3] = f2bf(f.w);
    *(short4v*)(dst + i) = o;
}

// -------- posemb: hs_bf16 = fp32(hidden) + pos * W_pe + b_pe --------
__global__ void posemb_k(const float* __restrict__ hid, const float* __restrict__ wpe,
                         const float* __restrict__ bpe, short* __restrict__ hs) {
    long long idx = (long long)blockIdx.x * blockDim.x + threadIdx.x;
    long long base = idx * 8;
    int c = (int)(base & (HIDN - 1));
    int s = (int)((base >> 10) & (SEQ - 1));
    float pos = (float)(s - 512) * (1.0f / 512.0f);
    float4 h0 = *(const float4*)(hid + base);
    float4 h1 = *(const float4*)(hid + base + 4);
    float4 w0 = *(const float4*)(wpe + c);
    float4 w1 = *(const float4*)(wpe + c + 4);
    float4 b0 = *(const float4*)(bpe + c);
    float4 b1 = *(const float4*)(bpe + c + 4);
    short8 ov;
    ov[0] = f2bf(h0.x + pos * w0.x + b0.x);
    ov[1] = f2bf(h0.y + pos * w0.y + b0.y);
    ov[2] = f2bf(h0.z + pos * w0.z + b0.z);
    ov[3] = f2bf(h0.w + pos * w0.w + b0.w);
    ov[4] = f2bf(h1.x + pos * w1.x + b1.x);
    ov[5] = f2bf(h1.y + pos * w1.y + b1.y);
    ov[6] = f2bf(h1.z + pos * w1.z + b1.z);
    ov[7] = f2bf(h1.w + pos * w1.w + b1.w);
    *(short8*)(hs + base) = ov;
}

// -------- GEMM: C = A(bf16) @ W(bf16)^T + bias(fp32) --------
// M=16384, N=1024, K=1024. 128x128 tile, BK=32, 256 threads (4 waves 2x2).
// MODE 0: write fp32 C[m][n] row-major (out-proj). MODE 1: write bf16 [B,H,S,D].
template <int MODE>
__global__ __launch_bounds__(256) void gemm_nt(const short* __restrict__ A,
                                               const short* __restrict__ W,
                                               const float* __restrict__ bias,
                                               void* __restrict__ Cout) {
    __shared__ __align__(16) short Als[128 * 32];
    __shared__ __align__(16) short Bls[128 * 32];
    const int tid  = threadIdx.x;
    const int lane = tid & 63;
    const int w    = tid >> 6;
    const int wr   = w >> 1, wc = w & 1;
    const int tm   = blockIdx.y * 128;
    const int tn   = blockIdx.x * 128;

    f32x4 acc[4][4] = {};

    const int srow = tid >> 2;            // 0..63
    const int skb  = (tid & 3) * 8;       // k sub-offset
    const long long a_base = (long long)(tm + srow) * 1024 + skb;
    const long long b_base = (long long)(tn + srow) * 1024 + skb;
    const int ldsw = w * 1024;            // wave-uniform LDS byte base

    const int fr = lane & 15;
    const int fg = (lane >> 4) * 8;

    for (int k0 = 0; k0 < 1024; k0 += 32) {
#pragma unroll
        for (int i = 0; i < 2; ++i) {
            gload_lds16((const void*)(A + a_base + (long long)i * 64 * 1024 + k0),
                        (void*)((char*)Als + i * 4096 + ldsw));
            gload_lds16((const void*)(W + b_base + (long long)i * 64 * 1024 + k0),
                        (void*)((char*)Bls + i * 4096 + ldsw));
        }
        __syncthreads();
        short8 af[4], bfr[4];
#pragma unroll
        for (int r = 0; r < 4; ++r) {
            af[r]  = *(const short8*)(Als + (wr * 64 + r * 16 + fr) * 32 + fg);
            bfr[r] = *(const short8*)(Bls + (wc * 64 + r * 16 + fr) * 32 + fg);
        }
#pragma unroll
        for (int mi = 0; mi < 4; ++mi)
#pragma unroll
            for (int ni = 0; ni < 4; ++ni)
                acc[mi][ni] = __builtin_amdgcn_mfma_f32_16x16x32_bf16(af[mi], bfr[ni], acc[mi][ni], 0, 0, 0);
        __syncthreads();
    }

    const int g4 = (lane >> 4) * 4;
#pragma unroll
    for (int ni = 0; ni < 4; ++ni) {
        int col = tn + wc * 64 + ni * 16 + fr;
        float bv = bias[col];
#pragma unroll
        for (int mi = 0; mi < 4; ++mi) {
#pragma unroll
            for (int r = 0; r < 4; ++r) {
                int row = tm + wr * 64 + mi * 16 + g4 + r;
                float val = acc[mi][ni][r] + bv;
                if (MODE == 0) {
                    ((float*)Cout)[(long long)row * 1024 + col] = val;
                } else {
                    int b = row >> 10, s = row & 1023;
                    int h = col >> 6, d = col & 63;
                    ((short*)Cout)[(((long long)(b * NH + h) * SEQ + s) << 6) + d] = f2bf(val);
                }
            }
        }
    }
}

// -------- attention v3: swapped QK^T + in-register P (v2, algebra-verified)
//          + round-4 V^T LDS path (HW-verified). No tr_read, no LDS casts. --------
// grid: x = q-tile (8), y = b*h (256). 256 threads = 4 waves, wave owns 32 q-rows.
__global__ __launch_bounds__(256) void attn_k(const short* __restrict__ Q,
                                              const short* __restrict__ Kg,
                                              const short* __restrict__ Vg,
                                              const float* __restrict__ pbias,
                                              short* __restrict__ ctx) {
    __shared__ __align__(16) short Kls[128 * 72];   // K tile [key][d], pad 72
    __shared__ __align__(16) short Vls[64 * 136];   // V^T tile [d][key], pad 136 (round-4 verified)
    __shared__ __align__(16) float pbl[SEQ];        // pos_bias head slice

    const int tid  = threadIdx.x;
    const int lane = tid & 63;
    const int w    = tid >> 6;
    const int bh   = blockIdx.y;
    const int h    = bh & (NH - 1);
    const int qt   = blockIdx.x;
    const long long base = (long long)bh * (SEQ * HD);

    const int fr = lane & 15;
    const int g  = lane >> 4;

    {   // stage pos_bias head slice (once per block; barrier before first use below)
        const float* pbh = pbias + h * PBSTRIDE;
        for (int i = tid; i < SEQ; i += 256) pbl[i] = pbh[i];
    }

    // Q fragments (B-operand of swapped QK^T): lane holds Q[q=qt*128+w*32+qb*16+fr][d=ks*32+g*8..+7]
    // 1/sqrt(64)=0.125 folded in (exact in bf16).
    short8 qf[2][2];
#pragma unroll
    for (int qb = 0; qb < 2; ++qb)
#pragma unroll
        for (int ks = 0; ks < 2; ++ks) {
            short8 t = *(const short8*)(Q + base + (long long)(qt * 128 + w * 32 + qb * 16 + fr) * HD + ks * 32 + g * 8);
#pragma unroll
            for (int j = 0; j < 8; ++j) t[j] = f2bf(bf2f(t[j]) * 0.125f);
            qf[qb][ks] = t;
        }

    f32x4 o2[2][4] = {};
    float mrun[2] = { -1e30f, -1e30f };
    float lrun[2] = { 0.0f, 0.0f };

    const int rrow = tid >> 3;            // 0..31
    const int dcol = (tid & 7) * 8;       // 0..56

    for (int kt = 0; kt < 8; ++kt) {
        __syncthreads();  // protect K/V LDS against previous iteration's reads
#pragma unroll
        for (int i = 0; i < 4; ++i) {     // round-4 verified staging
            const long long grow = base + (long long)(kt * 128 + i * 32 + rrow) * HD + dcol;
            short8 kv = *(const short8*)(Kg + grow);
            *(short8*)(Kls + (i * 32 + rrow) * 72 + dcol) = kv;
            short8 vv = *(const short8*)(Vg + grow);
#pragma unroll
            for (int j = 0; j < 8; ++j)
                Vls[(dcol + j) * 136 + i * 32 + rrow] = vv[j];
        }
        __syncthreads();

        // S^T = K Q^T : lane holds S[key = kt*128 + ni*16 + 4g + r][q = qb*16 + fr]
        f32x4 sc[8][2] = {};
#pragma unroll
        for (int ni = 0; ni < 8; ++ni) {
#pragma unroll
            for (int ks = 0; ks < 2; ++ks) {
                short8 kf = *(const short8*)(Kls + (ni * 16 + fr) * 72 + ks * 32 + g * 8);
                sc[ni][0] = __builtin_amdgcn_mfma_f32_16x16x32_bf16(kf, qf[0][ks], sc[ni][0], 0, 0, 0);
                sc[ni][1] = __builtin_amdgcn_mfma_f32_16x16x32_bf16(kf, qf[1][ks], sc[ni][1], 0, 0, 0);
            }
        }

        // + learned key bias (lane keys ni*16 + 4g + r -> aligned float4 at ni*16 + g*4)
#pragma unroll
        for (int ni = 0; ni < 8; ++ni) {
            f32x4 pb4 = *(const f32x4*)(pbl + kt * 128 + ni * 16 + g * 4);
#pragma unroll
            for (int r = 0; r < 4; ++r) {
                sc[ni][0][r] += pb4[r];
                sc[ni][1][r] += pb4[r];
            }
        }

        // online softmax per q-row (each lane holds 32 keys of q=qb*16+fr; reduce over g-groups)
        unsigned p2[2][8][2];
        float sclq[2];
#pragma unroll
        for (int qb = 0; qb < 2; ++qb) {
            float mx = sc[0][qb][0];
#pragma unroll
            for (int ni = 0; ni < 8; ++ni)
#pragma unroll
                for (int r = 0; r < 4; ++r) mx = fmaxf(mx, sc[ni][qb][r]);
            mx = fmaxf(mx, __shfl_xor(mx, 16));
            mx = fmaxf(mx, __shfl_xor(mx, 32));
            float mnew = fmaxf(mrun[qb], mx);
            float scl  = __expf(mrun[qb] - mnew);
            mrun[qb] = mnew;
            lrun[qb] *= scl;
            sclq[qb] = scl;
            float ps = 0.0f;
#pragma unroll
            for (int ni = 0; ni < 8; ++ni)
#pragma unroll
                for (int r = 0; r < 4; ++r) {
                    float p = __expf(sc[ni][qb][r] - mnew);
                    sc[ni][qb][r] = p;
                    ps += p;
                }
            ps += __shfl_xor(ps, 16);
            ps += __shfl_xor(ps, 32);
            lrun[qb] += ps;
#pragma unroll
            for (int ni = 0; ni < 8; ++ni)
#pragma unroll
                for (int c = 0; c < 2; ++c)
                    p2[qb][ni][c] = pack2(f2bf(sc[ni][qb][2 * c]), f2bf(sc[ni][qb][2 * c + 1]));
        }

        // rescale O (O-frag rows q = qb*16 + 4g + r; scl lives at lane fr = 4g+r, g=0)
#pragma unroll
        for (int qb = 0; qb < 2; ++qb)
#pragma unroll
            for (int r = 0; r < 4; ++r) {
                float s_r = __shfl(sclq[qb], 4 * g + r);
#pragma unroll
                for (int di = 0; di < 4; ++di) o2[qb][di][r] *= s_r;
            }

        // Redistribute P into PV A-fragments: lane needs P[q=qb*16+fr][key=32ks+8g+j]
        // dword t (keys 8g+2t,+1): src lane = fr + 32*(g&1) + 16*(t>>1); reg = p2[qb][2ks+(g>=2)][t&1]
        short8 pfrag[2][4];
        {
            const int srcl0 = fr + 32 * (g & 1);
            const int srcl1 = srcl0 + 16;
            const bool hi = (g & 2) != 0;
#pragma unroll
            for (int qb = 0; qb < 2; ++qb)
#pragma unroll
                for (int ks = 0; ks < 4; ++ks) {
                    union { short8 s8; unsigned u[4]; } pu;
#pragma unroll
                    for (int t = 0; t < 4; ++t) {
                        const int srcl = (t < 2) ? srcl0 : srcl1;
                        unsigned s0 = __shfl(p2[qb][2 * ks][t & 1], srcl);
                        unsigned s1 = __shfl(p2[qb][2 * ks + 1][t & 1], srcl);
                        pu.u[t] = hi ? s1 : s0;
                    }
                    pfrag[qb][ks] = pu.s8;
                }
        }

        // O += P V : B-frag from V^T LDS (round-4 verified addresses)
#pragma unroll
        for (int ks = 0; ks < 4; ++ks) {
#pragma unroll
            for (int di = 0; di < 4; ++di) {
                short8 vb = *(const short8*)(Vls + (di * 16 + fr) * 136 + ks * 32 + g * 8);
                o2[0][di] = __builtin_amdgcn_mfma_f32_16x16x32_bf16(pfrag[0][ks], vb, o2[0][di], 0, 0, 0);
                o2[1][di] = __builtin_amdgcn_mfma_f32_16x16x32_bf16(pfrag[1][ks], vb, o2[1][di], 0, 0, 0);
            }
        }
    }

    // normalize + store ctx [B,S,HID]; O-frag: lane holds O[q=qb*16+4g+r][d=di*16+fr]
    const int b = bh >> 4;
#pragma unroll
    for (int qb = 0; qb < 2; ++qb) {
#pragma unroll
        for (int r = 0; r < 4; ++r) {
            float lv  = __shfl(lrun[qb], 4 * g + r);
            float inv = 1.0f / lv;
            int row = qt * 128 + w * 32 + qb * 16 + 4 * g + r;
#pragma unroll
            for (int di = 0; di < 4; ++di)
                ctx[(long long)(b * SEQ + row) * HIDN + h * HD + di * 16 + fr] = f2bf(o2[qb][di][r] * inv);
        }
    }
}

// ---------------- launcher ----------------
extern "C" void kernel_launch(void* const* d_in, const int* in_sizes, int n_in,
                              void* d_out, int out_size, void* d_ws, size_t ws_size,
                              hipStream_t stream) {
    const float* hid  = (const float*)d_in[0];
    const float* Wq   = (const float*)d_in[1];
    const float* bq   = (const float*)d_in[2];
    const float* Wk   = (const float*)d_in[3];
    const float* bk   = (const float*)d_in[4];
    const float* Wv   = (const float*)d_in[5];
    const float* bv   = (const float*)d_in[6];
    const float* Wo   = (const float*)d_in[7];
    const float* bo   = (const float*)d_in[8];
    const float* Wpe  = (const float*)d_in[9];
    const float* bpe  = (const float*)d_in[10];
    const float* pbias = (const float*)d_in[11];

    const long long NE = (long long)BATCH * SEQ * HIDN;  // 16M elements
    const long long WSZ = (long long)HIDN * HIDN;        // 1M elements per weight

    // ws (shorts): hs [0,NE) | v [NE,2NE) | Wc_q/k/v/o — 72 MB total (ws >= 96 MB proven)
    short* hs   = (short*)d_ws;
    short* v    = hs + NE;
    short* Wcq  = v + NE;
    short* Wck  = Wcq + WSZ;
    short* Wcv  = Wck + WSZ;
    short* Wco  = Wcv + WSZ;
    // d_out (fp32 out, 64 MB): q [0,NE) shorts | k [NE,2NE) shorts — dead before final GEMM overwrites
    short* q    = (short*)d_out;
    short* k    = q + NE;
    short* ctx  = hs;  // alias: hs dead after QKV projections

    posemb_k<<<(int)(NE / 8 / 256), 256, 0, stream>>>(hid, Wpe, bpe, hs);
    convw_k<<<(int)(WSZ / 4 / 256), 256, 0, stream>>>(Wq, Wcq);
    convw_k<<<(int)(WSZ / 4 / 256), 256, 0, stream>>>(Wk, Wck);
    convw_k<<<(int)(WSZ / 4 / 256), 256, 0, stream>>>(Wv, Wcv);
    convw_k<<<(int)(WSZ / 4 / 256), 256, 0, stream>>>(Wo, Wco);

    dim3 gg(8, 128);  // N tiles x M tiles
    gemm_nt<1><<<gg, 256, 0, stream>>>(hs, Wcq, bq, q);
    gemm_nt<1><<<gg, 256, 0, stream>>>(hs, Wck, bk, k);
    gemm_nt<1><<<gg, 256, 0, stream>>>(hs, Wcv, bv, v);

    attn_k<<<dim3(8, 256), 256, 0, stream>>>(q, k, v, pbias, ctx);

    gemm_nt<0><<<gg, 256, 0, stream>>>(ctx, Wco, bo, d_out);
}